// Round 9
// baseline (451.829 us; speedup 1.0000x reference)
//
#include <hip/hip_runtime.h>

#define NNODES 100000
#define NEDGES 1250000
#define IN_CH 128
#define HID 64
#define BN_EPS 1e-5f

#define NPAD 100352               // NNODES rounded to 256 multiple
#define NB 4                      // source-range buckets per node
#define BKT_DIV 25000             // bucket = src / 25000
#define C4LEN (NB * NPAD)         // 401408 bucketed-count array length
#define SCAN1_BLOCKS (C4LEN / 256)  // 1568
#define DRANGE 12500              // NNODES / 8 (dst range per XCD)
#define FILL_CHUNK 2048           // edges per block in filtered count/fill
#define FILL_CHUNKS 611           // ceil(NEDGES / FILL_CHUNK)
#define GGROUPS 12500             // gather node groups (8 nodes each)

typedef __attribute__((ext_vector_type(8))) short s16x8;   // 8 bf16 (4 VGPRs)
typedef __attribute__((ext_vector_type(4))) float f32x4;

// bf16 <-> f32 helpers (bit-level, no __hip_bfloat16 class dependence)
__device__ __forceinline__ ushort f2bf(float f) {
    union { float f; unsigned int i; } c;
    c.f = f;
    unsigned int lsb = (c.i >> 16) & 1u;
    return (ushort)((c.i + 0x7FFFu + lsb) >> 16);   // round-to-nearest-even
}
__device__ __forceinline__ float bf2f(ushort u) {
    union { unsigned int i; float f; } c;
    c.i = (unsigned int)u << 16;
    return c.f;
}

// ---------------- bucketed CSR build (dst-range partitioned by XCD) -------
// cnt4 index = d*4 + bucket(src): each row's srcs segment is subdivided into
// 4 contiguous sub-segments in ascending source range -> co-resident gather
// waves sweep source space together (L2 band locality), rows stay contiguous.
__global__ void csr_zero(int* cnt4) {
    int i = blockIdx.x * blockDim.x + threadIdx.x;
    if (i < C4LEN) cnt4[i] = 0;
}

// block b -> XCD b&7 (round-robin dispatch heuristic) -> dst range
// [p*DRANGE, (p+1)*DRANGE). Each XCD streams the whole edge list (redundant
// reads served by L2/L3) but its atomic lines stay XCD-local.
__global__ void csr_count(const int* __restrict__ src, const int* __restrict__ dst,
                          int* cnt4) {
    int p = blockIdx.x & 7;
    int base = (blockIdx.x >> 3) * FILL_CHUNK;
    int lo = p * DRANGE, hi = lo + DRANGE;
#pragma unroll
    for (int k = 0; k < FILL_CHUNK / 256; ++k) {
        int e = base + k * 256 + threadIdx.x;
        if (e < NEDGES) {
            int d = dst[e];
            if (d >= lo && d < hi) {
                int bkt = src[e] / BKT_DIV;
                atomicAdd(&cnt4[d * NB + bkt], 1);
            }
        }
    }
}

// dis[i] = rsqrt(1 + total degree) from the 4 per-bucket counts (contiguous)
__global__ void make_dis(const int* __restrict__ cnt4, float* __restrict__ dis) {
    int i = blockIdx.x * blockDim.x + threadIdx.x;
    if (i >= NNODES) return;
    const int4 c = *(const int4*)(cnt4 + i * NB);
    dis[i] = rsqrtf((float)(1 + c.x + c.y + c.z + c.w));
}

// per-256-block exclusive scan of cnt4 -> row_ptr4, block sums -> bsum
__global__ void scan1(const int* __restrict__ cnt4, int* __restrict__ row_ptr4,
                      int* __restrict__ bsum) {
    __shared__ int s[256];
    int tid = threadIdx.x;
    int i = blockIdx.x * 256 + tid;
    int v = cnt4[i];
    s[tid] = v;
    __syncthreads();
    for (int off = 1; off < 256; off <<= 1) {
        int t = (tid >= off) ? s[tid - off] : 0;
        __syncthreads();
        s[tid] += t;
        __syncthreads();
    }
    row_ptr4[i] = s[tid] - v;                         // exclusive within block
    if (tid == 255) bsum[blockIdx.x] = s[255];        // block total
}

// single-block exclusive scan of SCAN1_BLOCKS block sums (chunked, carry)
__global__ void scan2(int* bsum) {
    __shared__ int s[1024];
    __shared__ int carry_s;
    int tid = threadIdx.x;
    if (tid == 0) carry_s = 0;
    __syncthreads();
    for (int base = 0; base < SCAN1_BLOCKS; base += 1024) {
        int idx = base + tid;
        int v = (idx < SCAN1_BLOCKS) ? bsum[idx] : 0;
        s[tid] = v;
        __syncthreads();
        for (int off = 1; off < 1024; off <<= 1) {
            int t = (tid >= off) ? s[tid - off] : 0;
            __syncthreads();
            s[tid] += t;
            __syncthreads();
        }
        int carry = carry_s;
        if (idx < SCAN1_BLOCKS) bsum[idx] = s[tid] - v + carry;
        __syncthreads();
        if (tid == 0) carry_s = carry + s[1023];
        __syncthreads();
    }
}

__global__ void scan3(int* __restrict__ row_ptr4, const int* __restrict__ bsum,
                      int* __restrict__ pos4) {
    int i = blockIdx.x * blockDim.x + threadIdx.x;
    if (i < C4LEN) {
        int v = row_ptr4[i] + bsum[i >> 8];
        row_ptr4[i] = v;
        pos4[i] = v;
    }
}

// Same dst-range filtering as csr_count: XCD p writes only its contiguous
// ~640 KB srcs region -> full line merging in its local L2.
__global__ void csr_fill(const int* __restrict__ src, const int* __restrict__ dst,
                         int* pos4, int* __restrict__ srcs) {
    int p = blockIdx.x & 7;
    int base = (blockIdx.x >> 3) * FILL_CHUNK;
    int lo = p * DRANGE, hi = lo + DRANGE;
#pragma unroll
    for (int k = 0; k < FILL_CHUNK / 256; ++k) {
        int e = base + k * 256 + threadIdx.x;
        if (e < NEDGES) {
            int d = dst[e];
            if (d >= lo && d < hi) {
                int s = src[e];
                int slot = atomicAdd(&pos4[d * NB + s / BKT_DIV], 1);
                srcs[slot] = s;
            }
        }
    }
}

// ---------------- fc + bn0 + relu (MFMA, 16 nodes x 64 cols per wave) -----
// h0[i][j] = bf16( relu(bn0(sum_k x[i][k]*w[k][j] + b[j])) )
__global__ __launch_bounds__(256) void fc_bn_relu(
        const float* __restrict__ x, const float* __restrict__ w,
        const float* __restrict__ b,
        const float* __restrict__ g, const float* __restrict__ be,
        const float* __restrict__ mu, const float* __restrict__ var,
        ushort* __restrict__ h0) {
    const int wave = threadIdx.x >> 6;
    const int lane = threadIdx.x & 63;
    const int m = lane & 15;
    const int q = lane >> 4;
    const int node_base = (blockIdx.x * 4 + wave) * 16;

    // B fragments: 4 k-chunks x 4 col-tiles (w is 128x64, L1/L2 resident)
    s16x8 bfrag[4][4];
#pragma unroll
    for (int kc = 0; kc < 4; ++kc)
#pragma unroll
        for (int ct = 0; ct < 4; ++ct)
#pragma unroll
            for (int j = 0; j < 8; ++j)
                bfrag[kc][ct][j] = (short)f2bf(w[(kc * 32 + q * 8 + j) * HID + ct * 16 + m]);

    f32x4 acc[4] = {{0,0,0,0},{0,0,0,0},{0,0,0,0},{0,0,0,0}};

    int row = node_base + m;
    if (row >= NNODES) row = NNODES - 1;             // clamp (stores guarded)
    const float4* xp = (const float4*)(x + (size_t)row * IN_CH + q * 8);

#pragma unroll
    for (int kc = 0; kc < 4; ++kc) {
        float4 a0 = xp[kc * 8 + 0];                  // k = kc*32 + q*8 + 0..3
        float4 a1 = xp[kc * 8 + 1];                  // k = kc*32 + q*8 + 4..7
        s16x8 af;
        af[0] = (short)f2bf(a0.x); af[1] = (short)f2bf(a0.y);
        af[2] = (short)f2bf(a0.z); af[3] = (short)f2bf(a0.w);
        af[4] = (short)f2bf(a1.x); af[5] = (short)f2bf(a1.y);
        af[6] = (short)f2bf(a1.z); af[7] = (short)f2bf(a1.w);
#pragma unroll
        for (int ct = 0; ct < 4; ++ct)
            acc[ct] = __builtin_amdgcn_mfma_f32_16x16x32_bf16(af, bfrag[kc][ct], acc[ct], 0, 0, 0);
    }

#pragma unroll
    for (int ct = 0; ct < 4; ++ct) {
        int col = ct * 16 + m;
        float sc = g[col] * rsqrtf(var[col] + BN_EPS);
        float off = (b[col] - mu[col]) * sc + be[col];
#pragma unroll
        for (int r = 0; r < 4; ++r) {
            int node = node_base + q * 4 + r;
            if (node < NNODES)
                h0[(size_t)node * HID + col] = f2bf(fmaxf(acc[ct][r] * sc + off, 0.f));
        }
    }
}

// ---------------- conv matmul + source-side dis scale (MFMA, bf16 in) -----
// hws[i][j] = bf16( dis[i] * sum_k h[i][k] * w[k][j] ),  K = 64, h is bf16
__global__ __launch_bounds__(256) void conv_mm(
        const ushort* __restrict__ h, const float* __restrict__ w,
        const float* __restrict__ dis, ushort* __restrict__ hws) {
    const int wave = threadIdx.x >> 6;
    const int lane = threadIdx.x & 63;
    const int m = lane & 15;
    const int q = lane >> 4;
    const int node_base = (blockIdx.x * 4 + wave) * 16;

    s16x8 bfrag[2][4];
#pragma unroll
    for (int kc = 0; kc < 2; ++kc)
#pragma unroll
        for (int ct = 0; ct < 4; ++ct)
#pragma unroll
            for (int j = 0; j < 8; ++j)
                bfrag[kc][ct][j] = (short)f2bf(w[(kc * 32 + q * 8 + j) * HID + ct * 16 + m]);

    f32x4 acc[4] = {{0,0,0,0},{0,0,0,0},{0,0,0,0},{0,0,0,0}};

    int row = node_base + m;
    if (row >= NNODES) row = NNODES - 1;
    const s16x8* hp = (const s16x8*)(h + (size_t)row * HID);   // 8 bf16 = 16B

#pragma unroll
    for (int kc = 0; kc < 2; ++kc) {
        s16x8 af = hp[kc * 4 + q];                   // k = kc*32 + q*8 + 0..7
#pragma unroll
        for (int ct = 0; ct < 4; ++ct)
            acc[ct] = __builtin_amdgcn_mfma_f32_16x16x32_bf16(af, bfrag[kc][ct], acc[ct], 0, 0, 0);
    }

    float dv[4];
#pragma unroll
    for (int r = 0; r < 4; ++r) {
        int node = node_base + q * 4 + r;
        dv[r] = (node < NNODES) ? dis[node] : 0.f;
    }
#pragma unroll
    for (int ct = 0; ct < 4; ++ct) {
        int col = ct * 16 + m;
#pragma unroll
        for (int r = 0; r < 4; ++r) {
            int node = node_base + q * 4 + r;
            if (node < NNODES)
                hws[(size_t)node * HID + col] = f2bf(acc[ct][r] * dv[r]);
        }
    }
}

// ---------------- gather + epilogue (column-sliced by XCD) ----------------
// Block b: slice = ((b&7)>=4) -> columns [slice*32, slice*32+32) = one 64B
// line of each bf16 row. Wave = 2 nodes x 32 cols; block of 256 = 8 nodes.
// Rows' srcs segments are bucket-ordered (coarse ascending src) -> band
// locality in L2. Output: bf16 (layer 1, to ws) or f32 (layer 2, to d_out).
__global__ void gather_update(const ushort* __restrict__ hws,
                              const int* __restrict__ row_ptr4,
                              const int* __restrict__ srcs, const float* __restrict__ dis,
                              const float* __restrict__ bias,
                              const float* __restrict__ g, const float* __restrict__ be,
                              const float* __restrict__ mu, const float* __restrict__ var,
                              const ushort* __restrict__ last,
                              ushort* __restrict__ out_bf, float* __restrict__ out_f,
                              int write_f32) {
    int b = blockIdx.x;
    int slice = (b >> 2) & 1;                       // == ((b&7) >= 4)
    int group = ((b >> 3) << 2) | (b & 3);          // [0, GGROUPS)
    int wave = threadIdx.x >> 6;
    int lane = threadIdx.x & 63;
    int d = group * 8 + wave * 2 + (lane >> 5);
    if (d >= NNODES) return;
    int col = slice * 32 + (lane & 31);

    float acc = bf2f(hws[(size_t)d * HID + col]);   // self-loop
    int start = row_ptr4[d * NB];
    int n = row_ptr4[d * NB + NB] - start;          // padded rows have 0 count
    const int* sp = srcs + start;

    int k = 0;
    for (; k + 3 < n; k += 4) {                     // unroll 4 for load ILP
        int s0 = __builtin_nontemporal_load(sp + k + 0);
        int s1 = __builtin_nontemporal_load(sp + k + 1);
        int s2 = __builtin_nontemporal_load(sp + k + 2);
        int s3 = __builtin_nontemporal_load(sp + k + 3);
        float v0 = bf2f(hws[(size_t)s0 * HID + col]);
        float v1 = bf2f(hws[(size_t)s1 * HID + col]);
        float v2 = bf2f(hws[(size_t)s2 * HID + col]);
        float v3 = bf2f(hws[(size_t)s3 * HID + col]);
        acc += v0 + v1 + v2 + v3;
    }
    for (; k < n; ++k) acc += bf2f(hws[(size_t)__builtin_nontemporal_load(sp + k) * HID + col]);

    float v = acc * dis[d] + bias[col];
    v = (v - mu[col]) * (g[col] * rsqrtf(var[col] + BN_EPS)) + be[col];
    v = fmaxf(v, 0.f) + bf2f(last[(size_t)d * HID + col]);
    if (write_f32) out_f[(size_t)d * HID + col] = v;
    else           out_bf[(size_t)d * HID + col] = f2bf(v);
}

extern "C" void kernel_launch(void* const* d_in, const int* in_sizes, int n_in,
                              void* d_out, int out_size, void* d_ws, size_t ws_size,
                              hipStream_t stream) {
    const float* x      = (const float*)d_in[0];
    const int*   eidx   = (const int*)d_in[1];
    const float* fc_w   = (const float*)d_in[2];
    const float* fc_b   = (const float*)d_in[3];
    const float* conv_w = (const float*)d_in[4];
    const float* conv_b = (const float*)d_in[5];
    const float* bn_g   = (const float*)d_in[6];
    const float* bn_b   = (const float*)d_in[7];
    const float* bn_m   = (const float*)d_in[8];
    const float* bn_v   = (const float*)d_in[9];

    const int* src = eidx;
    const int* dst = eidx + NEDGES;

    float* out = (float*)d_out;       // final output (f32), written once

    // workspace (4B words): dis | cnt4 | row_ptr4 | pos4 | bsum | srcs |
    //                       h0(bf16) | h1(bf16) | hws(bf16)
    float*  dis      = (float*)d_ws;
    int*    cnt4     = (int*)(dis + NPAD);
    int*    row_ptr4 = cnt4 + C4LEN;
    int*    pos4     = row_ptr4 + C4LEN;
    int*    bsum     = pos4 + C4LEN;
    int*    srcs     = bsum + 2048;
    ushort* h0       = (ushort*)(srcs + NEDGES);      // N*64 bf16 = 12.8 MB
    ushort* h1       = h0 + (size_t)NNODES * HID;
    ushort* hws      = h1 + (size_t)NNODES * HID;

    const int BLK = 256;
    const int gridN   = (NNODES + BLK - 1) / BLK;
    const int gridC4  = C4LEN / BLK;                     // 1568
    const int gridF   = FILL_CHUNKS * 8;                 // 4888 (filtered count/fill)
    const int gridGA  = GGROUPS * 2;                     // 25000 (sliced gather)
    const int gridMM  = (NNODES + 63) / 64;              // 1563 (MFMA matmuls)

    // bucketed CSR build + degree (dst-range partitioned)
    csr_zero<<<gridC4, BLK, 0, stream>>>(cnt4);
    csr_count<<<gridF, BLK, 0, stream>>>(src, dst, cnt4);
    make_dis<<<gridN, BLK, 0, stream>>>(cnt4, dis);
    scan1<<<SCAN1_BLOCKS, 256, 0, stream>>>(cnt4, row_ptr4, bsum);
    scan2<<<1, 1024, 0, stream>>>(bsum);
    scan3<<<gridC4, BLK, 0, stream>>>(row_ptr4, bsum, pos4);
    csr_fill<<<gridF, BLK, 0, stream>>>(src, dst, pos4, srcs);

    // fc + bn0 + relu -> h0 (bf16 residual). h0 is never overwritten.
    fc_bn_relu<<<gridMM, BLK, 0, stream>>>(x, fc_w, fc_b, bn_g, bn_b, bn_m, bn_v, h0);

    // layer 1: h0 -> hws -> h1 (bf16)
    conv_mm<<<gridMM, BLK, 0, stream>>>(h0, conv_w, dis, hws);
    gather_update<<<gridGA, BLK, 0, stream>>>(hws, row_ptr4, srcs, dis,
                                              conv_b, bn_g + HID, bn_b + HID,
                                              bn_m + HID, bn_v + HID, h0,
                                              h1, nullptr, 0);

    // layer 2: h1 -> hws -> out (f32, d_out)
    conv_mm<<<gridMM, BLK, 0, stream>>>(h1, conv_w + HID * HID, dis, hws);
    gather_update<<<gridGA, BLK, 0, stream>>>(hws, row_ptr4, srcs, dis,
                                              conv_b + HID, bn_g + 2 * HID, bn_b + 2 * HID,
                                              bn_m + 2 * HID, bn_v + 2 * HID, h0,
                                              nullptr, out, 1);
}

// Round 10
// 401.665 us; speedup vs baseline: 1.1249x; 1.1249x over previous
//
#include <hip/hip_runtime.h>

#define NNODES 100000
#define NEDGES 1250000
#define IN_CH 128
#define HID 64
#define BN_EPS 1e-5f

#define NPAD 100352               // NNODES rounded to 256 multiple
#define NSCAN_BLOCKS 391          // ceil(100000/256)
#define DRANGE 12500              // NNODES / 8 (dst range per XCD)
#define FILL_CHUNK 2048           // edges per block in filtered count/fill
#define FILL_CHUNKS 611           // ceil(NEDGES / FILL_CHUNK)
#define GGROUPS 6250              // gather groups: 16 nodes each (4 waves x 4)
#define PLANE ((size_t)NNODES * 16)   // one col-slice plane (bf16 elems)

typedef __attribute__((ext_vector_type(8))) short s16x8;   // 8 bf16 (4 VGPRs)
typedef __attribute__((ext_vector_type(4))) float f32x4;

// bf16 <-> f32 helpers (bit-level, no __hip_bfloat16 class dependence)
__device__ __forceinline__ ushort f2bf(float f) {
    union { float f; unsigned int i; } c;
    c.f = f;
    unsigned int lsb = (c.i >> 16) & 1u;
    return (ushort)((c.i + 0x7FFFu + lsb) >> 16);   // round-to-nearest-even
}
__device__ __forceinline__ float bf2f(ushort u) {
    union { unsigned int i; float f; } c;
    c.i = (unsigned int)u << 16;
    return c.f;
}

// ---------------- CSR build (dst-range partitioned by XCD) ----------------
__global__ void csr_zero(int* cnt) {
    int i = blockIdx.x * blockDim.x + threadIdx.x;
    if (i < NNODES) cnt[i] = 0;
}

// block b -> XCD b&7 (round-robin dispatch heuristic) -> dst range
// [p*DRANGE, (p+1)*DRANGE). Each XCD streams the whole dst[] (redundant reads
// served by L2/L3) but its atomic lines stay XCD-local.
__global__ void csr_count(const int* __restrict__ dst, int* cnt) {
    int p = blockIdx.x & 7;
    int base = (blockIdx.x >> 3) * FILL_CHUNK;
    int lo = p * DRANGE, hi = lo + DRANGE;
#pragma unroll
    for (int k = 0; k < FILL_CHUNK / 256; ++k) {
        int e = base + k * 256 + threadIdx.x;
        if (e < NEDGES) {
            int d = dst[e];
            if (d >= lo && d < hi) atomicAdd(&cnt[d], 1);
        }
    }
}

// per-256-block exclusive scan of cnt -> row_ptr, block sums -> bsum.
// Also emits dis[i] = rsqrt(cnt[i]+1)  (degree incl. self-loop).
__global__ void scan1(const int* __restrict__ cnt, int* __restrict__ row_ptr,
                      int* __restrict__ bsum, float* __restrict__ dis) {
    __shared__ int s[256];
    int tid = threadIdx.x;
    int i = blockIdx.x * 256 + tid;
    int v = (i < NNODES) ? cnt[i] : 0;
    if (i < NNODES) dis[i] = rsqrtf((float)(v + 1));
    s[tid] = v;
    __syncthreads();
    for (int off = 1; off < 256; off <<= 1) {
        int t = (tid >= off) ? s[tid - off] : 0;
        __syncthreads();
        s[tid] += t;
        __syncthreads();
    }
    if (i < NNODES) row_ptr[i] = s[tid] - v;          // exclusive
    if (tid == 255) bsum[blockIdx.x] = s[255];        // block total
}

// single-block exclusive scan of the 391 block sums (512 threads, padded)
__global__ void scan2(int* bsum) {
    __shared__ int s[512];
    int tid = threadIdx.x;
    int v = (tid < NSCAN_BLOCKS) ? bsum[tid] : 0;
    s[tid] = v;
    __syncthreads();
    for (int off = 1; off < 512; off <<= 1) {
        int t = (tid >= off) ? s[tid - off] : 0;
        __syncthreads();
        s[tid] += t;
        __syncthreads();
    }
    if (tid < NSCAN_BLOCKS) bsum[tid] = s[tid] - v;   // exclusive
}

__global__ void scan3(int* __restrict__ row_ptr, const int* __restrict__ bsum,
                      int* __restrict__ pos) {
    int i = blockIdx.x * blockDim.x + threadIdx.x;
    if (i < NNODES) {
        int v = row_ptr[i] + bsum[i >> 8];
        row_ptr[i] = v;
        pos[i] = v;
    }
}

// Same dst-range filtering: XCD p only writes srcs slots belonging to its dst
// range -> contiguous ~640 KB region, fully merged in its local L2.
__global__ void csr_fill(const int* __restrict__ src, const int* __restrict__ dst,
                         int* pos, int* __restrict__ srcs) {
    int p = blockIdx.x & 7;
    int base = (blockIdx.x >> 3) * FILL_CHUNK;
    int lo = p * DRANGE, hi = lo + DRANGE;
#pragma unroll
    for (int k = 0; k < FILL_CHUNK / 256; ++k) {
        int e = base + k * 256 + threadIdx.x;
        if (e < NEDGES) {
            int d = dst[e];
            if (d >= lo && d < hi) {
                int slot = atomicAdd(&pos[d], 1);
                srcs[slot] = src[e];
            }
        }
    }
}

// ---------------- fc + bn0 + relu (MFMA, 16 nodes x 64 cols per wave) -----
// h0 stored SLICE-MAJOR: h0[slice][node][16], slice = col>>4. Each 3.2 MB
// plane is the unit of XCD locality for the gather.
__global__ __launch_bounds__(256) void fc_bn_relu(
        const float* __restrict__ x, const float* __restrict__ w,
        const float* __restrict__ b,
        const float* __restrict__ g, const float* __restrict__ be,
        const float* __restrict__ mu, const float* __restrict__ var,
        ushort* __restrict__ h0) {
    const int wave = threadIdx.x >> 6;
    const int lane = threadIdx.x & 63;
    const int m = lane & 15;
    const int q = lane >> 4;
    const int node_base = (blockIdx.x * 4 + wave) * 16;

    // B fragments: 4 k-chunks x 4 col-tiles (w is 128x64, L1/L2 resident)
    s16x8 bfrag[4][4];
#pragma unroll
    for (int kc = 0; kc < 4; ++kc)
#pragma unroll
        for (int ct = 0; ct < 4; ++ct)
#pragma unroll
            for (int j = 0; j < 8; ++j)
                bfrag[kc][ct][j] = (short)f2bf(w[(kc * 32 + q * 8 + j) * HID + ct * 16 + m]);

    f32x4 acc[4] = {{0,0,0,0},{0,0,0,0},{0,0,0,0},{0,0,0,0}};

    int row = node_base + m;
    if (row >= NNODES) row = NNODES - 1;             // clamp (stores guarded)
    const float4* xp = (const float4*)(x + (size_t)row * IN_CH + q * 8);

#pragma unroll
    for (int kc = 0; kc < 4; ++kc) {
        float4 a0 = xp[kc * 8 + 0];                  // k = kc*32 + q*8 + 0..3
        float4 a1 = xp[kc * 8 + 1];                  // k = kc*32 + q*8 + 4..7
        s16x8 af;
        af[0] = (short)f2bf(a0.x); af[1] = (short)f2bf(a0.y);
        af[2] = (short)f2bf(a0.z); af[3] = (short)f2bf(a0.w);
        af[4] = (short)f2bf(a1.x); af[5] = (short)f2bf(a1.y);
        af[6] = (short)f2bf(a1.z); af[7] = (short)f2bf(a1.w);
#pragma unroll
        for (int ct = 0; ct < 4; ++ct)
            acc[ct] = __builtin_amdgcn_mfma_f32_16x16x32_bf16(af, bfrag[kc][ct], acc[ct], 0, 0, 0);
    }

#pragma unroll
    for (int ct = 0; ct < 4; ++ct) {
        int col = ct * 16 + m;
        float sc = g[col] * rsqrtf(var[col] + BN_EPS);
        float off = (b[col] - mu[col]) * sc + be[col];
#pragma unroll
        for (int r = 0; r < 4; ++r) {
            int node = node_base + q * 4 + r;
            if (node < NNODES)
                h0[(size_t)ct * PLANE + (size_t)node * 16 + m] =
                    f2bf(fmaxf(acc[ct][r] * sc + off, 0.f));
        }
    }
}

// ---------------- conv matmul + source-side dis scale (MFMA, sliced io) ---
// h (bf16, slice-major) -> hws (bf16, slice-major), K = 64
__global__ __launch_bounds__(256) void conv_mm(
        const ushort* __restrict__ h, const float* __restrict__ w,
        const float* __restrict__ dis, ushort* __restrict__ hws) {
    const int wave = threadIdx.x >> 6;
    const int lane = threadIdx.x & 63;
    const int m = lane & 15;
    const int q = lane >> 4;
    const int node_base = (blockIdx.x * 4 + wave) * 16;

    s16x8 bfrag[2][4];
#pragma unroll
    for (int kc = 0; kc < 2; ++kc)
#pragma unroll
        for (int ct = 0; ct < 4; ++ct)
#pragma unroll
            for (int j = 0; j < 8; ++j)
                bfrag[kc][ct][j] = (short)f2bf(w[(kc * 32 + q * 8 + j) * HID + ct * 16 + m]);

    f32x4 acc[4] = {{0,0,0,0},{0,0,0,0},{0,0,0,0},{0,0,0,0}};

    int row = node_base + m;
    if (row >= NNODES) row = NNODES - 1;

#pragma unroll
    for (int kc = 0; kc < 2; ++kc) {
        // k = kc*32 + q*8 + 0..7 -> slice kc*2 + (q>>1), offset (q&1)*8
        const s16x8* hp = (const s16x8*)(h + (size_t)(kc * 2 + (q >> 1)) * PLANE
                                           + (size_t)row * 16 + (q & 1) * 8);
        s16x8 af = *hp;
#pragma unroll
        for (int ct = 0; ct < 4; ++ct)
            acc[ct] = __builtin_amdgcn_mfma_f32_16x16x32_bf16(af, bfrag[kc][ct], acc[ct], 0, 0, 0);
    }

    float dv[4];
#pragma unroll
    for (int r = 0; r < 4; ++r) {
        int node = node_base + q * 4 + r;
        dv[r] = (node < NNODES) ? dis[node] : 0.f;
    }
#pragma unroll
    for (int ct = 0; ct < 4; ++ct) {
#pragma unroll
        for (int r = 0; r < 4; ++r) {
            int node = node_base + q * 4 + r;
            if (node < NNODES)
                hws[(size_t)ct * PLANE + (size_t)node * 16 + m] = f2bf(acc[ct][r] * dv[r]);
        }
    }
}

// ---------------- gather + epilogue (plane-per-XCD) -----------------------
// slice = b&3, group = b>>2: XCD p (= b&7) serves only slice p&3, so its
// random hws accesses stay inside one contiguous 3.2 MB plane < 4 MB L2.
// Wave = 4 nodes x 16 cols; block = 16 nodes. 6250 groups x 4 slices.
__global__ void gather_update(const ushort* __restrict__ hws,
                              const int* __restrict__ row_ptr, const int* __restrict__ cnt,
                              const int* __restrict__ srcs, const float* __restrict__ dis,
                              const float* __restrict__ bias,
                              const float* __restrict__ g, const float* __restrict__ be,
                              const float* __restrict__ mu, const float* __restrict__ var,
                              const ushort* __restrict__ last,
                              ushort* __restrict__ out_bf, float* __restrict__ out_f,
                              int write_f32) {
    int b = blockIdx.x;
    int slice = b & 3;
    int group = b >> 2;
    int wave = threadIdx.x >> 6;
    int lane = threadIdx.x & 63;
    int d = group * 16 + wave * 4 + (lane >> 4);     // < 100000 always
    int m = lane & 15;
    int col = slice * 16 + m;

    const ushort* hp = hws + (size_t)slice * PLANE;
    float acc = bf2f(hp[(size_t)d * 16 + m]);        // self-loop
    int start = row_ptr[d];
    int n = cnt[d];
    const int* sp = srcs + start;

    int k = 0;
    for (; k + 3 < n; k += 4) {                      // unroll 4 for load ILP
        int s0 = sp[k + 0], s1 = sp[k + 1], s2 = sp[k + 2], s3 = sp[k + 3];
        float v0 = bf2f(hp[(size_t)s0 * 16 + m]);
        float v1 = bf2f(hp[(size_t)s1 * 16 + m]);
        float v2 = bf2f(hp[(size_t)s2 * 16 + m]);
        float v3 = bf2f(hp[(size_t)s3 * 16 + m]);
        acc += v0 + v1 + v2 + v3;
    }
    for (; k < n; ++k) acc += bf2f(hp[(size_t)sp[k] * 16 + m]);

    float v = acc * dis[d] + bias[col];
    v = (v - mu[col]) * (g[col] * rsqrtf(var[col] + BN_EPS)) + be[col];
    v = fmaxf(v, 0.f) + bf2f(last[(size_t)slice * PLANE + (size_t)d * 16 + m]);
    if (write_f32) out_f[(size_t)d * HID + col] = v;             // full 64B line
    else           out_bf[(size_t)slice * PLANE + (size_t)d * 16 + m] = f2bf(v);
}

extern "C" void kernel_launch(void* const* d_in, const int* in_sizes, int n_in,
                              void* d_out, int out_size, void* d_ws, size_t ws_size,
                              hipStream_t stream) {
    const float* x      = (const float*)d_in[0];
    const int*   eidx   = (const int*)d_in[1];
    const float* fc_w   = (const float*)d_in[2];
    const float* fc_b   = (const float*)d_in[3];
    const float* conv_w = (const float*)d_in[4];
    const float* conv_b = (const float*)d_in[5];
    const float* bn_g   = (const float*)d_in[6];
    const float* bn_b   = (const float*)d_in[7];
    const float* bn_m   = (const float*)d_in[8];
    const float* bn_v   = (const float*)d_in[9];

    const int* src = eidx;
    const int* dst = eidx + NEDGES;

    float* out = (float*)d_out;       // final output (f32), written once

    // workspace (4B words): dis | cnt | row_ptr | pos | bsum | srcs |
    //                       h0(bf16 sliced) | h1 | hws
    float*  dis     = (float*)d_ws;
    int*    cnt     = (int*)(dis + NPAD);
    int*    row_ptr = cnt + NPAD;
    int*    pos     = row_ptr + NPAD;
    int*    bsum    = pos + NPAD;
    int*    srcs    = bsum + 512;
    ushort* h0      = (ushort*)(srcs + NEDGES);       // 4 planes of N*16 bf16
    ushort* h1      = h0 + 4 * PLANE;
    ushort* hws     = h1 + 4 * PLANE;

    const int BLK = 256;
    const int gridN   = (NNODES + BLK - 1) / BLK;
    const int gridF   = FILL_CHUNKS * 8;                 // 4888 (filtered count/fill)
    const int gridGA  = GGROUPS * 4;                     // 25000 (plane-sliced gather)
    const int gridMM  = (NNODES + 63) / 64;              // 1563 (MFMA matmuls)

    // CSR build + degree (dst-range partitioned)
    csr_zero<<<gridN, BLK, 0, stream>>>(cnt);
    csr_count<<<gridF, BLK, 0, stream>>>(dst, cnt);
    scan1<<<NSCAN_BLOCKS, 256, 0, stream>>>(cnt, row_ptr, bsum, dis);
    scan2<<<1, 512, 0, stream>>>(bsum);
    scan3<<<gridN, BLK, 0, stream>>>(row_ptr, bsum, pos);
    csr_fill<<<gridF, BLK, 0, stream>>>(src, dst, pos, srcs);

    // fc + bn0 + relu -> h0 (bf16 sliced residual). Never overwritten.
    fc_bn_relu<<<gridMM, BLK, 0, stream>>>(x, fc_w, fc_b, bn_g, bn_b, bn_m, bn_v, h0);

    // layer 1: h0 -> hws -> h1 (bf16 sliced)
    conv_mm<<<gridMM, BLK, 0, stream>>>(h0, conv_w, dis, hws);
    gather_update<<<gridGA, BLK, 0, stream>>>(hws, row_ptr, cnt, srcs, dis,
                                              conv_b, bn_g + HID, bn_b + HID,
                                              bn_m + HID, bn_v + HID, h0,
                                              h1, nullptr, 0);

    // layer 2: h1 -> hws -> out (f32, d_out)
    conv_mm<<<gridMM, BLK, 0, stream>>>(h1, conv_w + HID * HID, dis, hws);
    gather_update<<<gridGA, BLK, 0, stream>>>(hws, row_ptr, cnt, srcs, dis,
                                              conv_b + HID, bn_g + 2 * HID, bn_b + 2 * HID,
                                              bn_m + 2 * HID, bn_v + 2 * HID, h0,
                                              nullptr, out, 1);
}